// Round 1
// baseline (185.352 us; speedup 1.0000x reference)
//
#include <hip/hip_runtime.h>
#include <math.h>

// One thread per ray. Per-ray query is affine in depth: feat[c] = base[c] + d*slope[c],
// so op/vals are recomputable from depth alone -> stream everything, only the 64 fine
// depths need storage (LDS, lane-major => conflict-free).

#define NT 128
#define PTS 64
#define IMP 64
#define NRAYS (2*256*256)
#define NEARV 0.1f
#define STEPV (1.9f/63.0f)

__device__ __forceinline__ float sigmoidf(float x) {
    return 1.0f / (1.0f + expf(-x));
}

__global__ __launch_bounds__(NT) void nerf_main(
    const float* __restrict__ tm, const float* __restrict__ wq,
    float* __restrict__ out, unsigned int* __restrict__ mmx)
{
    __shared__ float fd[IMP][NT];   // fine depths, [k][lane] -> bank-conflict-free
    const int tid = threadIdx.x;
    const int r = blockIdx.x * NT + tid;
    const int b = r >> 16;          // batch
    const int n = r & 65535;        // pixel within batch
    const int i = n >> 8;           // row (W-dim of meshgrid)
    const int j = n & 255;          // col (H-dim of meshgrid)

    // camera dir: (lin(j)/F, lin(i)/F, 1), lin(k) = 1 - 2k/255
    const float lx = 1.0f + (float)j * (-2.0f/255.0f);
    const float ly = 1.0f + (float)i * (-2.0f/255.0f);
    const float cx = lx / 4.2f;
    const float cy = ly / 4.2f;

    const float* tmb = tm + b*12;   // (3,4) row-major: cols 0..2 = R, col 3 = t
    const float dx = tmb[0]*cx + tmb[1]*cy + tmb[2];
    const float dy = tmb[4]*cx + tmb[5]*cy + tmb[6];
    const float dz = tmb[8]*cx + tmb[9]*cy + tmb[10];
    const float ox = tmb[3], oy = tmb[7], oz = tmb[11];

    // feat[c] = base[c] + d*slope[c]
    float base[4], slp[4];
    #pragma unroll
    for (int c = 0; c < 4; c++) {
        slp[c]  = dx*wq[0*4+c] + dy*wq[1*4+c] + dz*wq[2*4+c];
        base[c] = ox*wq[0*4+c] + oy*wq[1*4+c] + oz*wq[2*4+c]
                + dx*wq[3*4+c] + dy*wq[4*4+c] + dz*wq[5*4+c];
    }

    // ---- coarse march: accumulate c_img and S = sum(w + 1e-5) ----
    float T = 1.0f, S = 0.0f, a0 = 0.0f, a1 = 0.0f, a2 = 0.0f;
    for (int p = 0; p < PTS; p++) {
        float d  = NEARV + (float)p * STEPV;
        float op = sigmoidf(base[0] + d*slp[0]);
        float v0 = sigmoidf(base[1] + d*slp[1]);
        float v1 = sigmoidf(base[2] + d*slp[2]);
        float v2 = sigmoidf(base[3] + d*slp[3]);
        float w  = op * T;
        a0 += w*v0; a1 += w*v1; a2 += w*v2;
        S  += w + 1e-5f;
        T  *= (1.0f - op);
    }
    out[(b*3+0)*65536 + n] = a0;
    out[(b*3+1)*65536 + n] = a1;
    out[(b*3+2)*65536 + n] = a2;

    // ---- streaming inverse-CDF sampling (searchsorted right, u ascending) ----
    float T2, c_lo = 0.0f, c_hi;
    {
        float op = sigmoidf(base[0] + NEARV*slp[0]);
        c_hi = (op + 1e-5f) / S;   // cdf[0]  (w0 = op*1)
        T2   = 1.0f - op;
    }
    int ind = 0;                   // invariant: c_hi = cdf[ind], c_lo = cdf[ind-1]
    float bin_prev = 0.0f;
    for (int k = 0; k <= IMP; k++) {
        float u = (float)k * (1.0f/64.0f);
        while (ind < PTS && c_hi <= u) {
            ind++;
            if (ind < PTS) {
                float d  = NEARV + (float)ind * STEPV;
                float op = sigmoidf(base[0] + d*slp[0]);
                float w  = op * T2;
                T2  *= (1.0f - op);
                c_lo = c_hi;
                c_hi = c_hi + (w + 1e-5f) / S;
            }
        }
        float bin;
        if (ind == 0) {
            bin = NEARV;                       // below=above=0 -> d0
        } else if (ind >= PTS) {
            bin = NEARV + 63.0f*STEPV;         // below=above=63 -> d63
        } else {
            float d0 = NEARV + (float)(ind-1) * STEPV;
            float d1 = NEARV + (float)ind * STEPV;
            float denom = c_hi - c_lo;
            denom = (denom < 1e-8f) ? 1.0f : denom;   // never triggers (gap >= 1e-5/S)
            float t = (u - c_lo) / denom;
            t = fminf(fmaxf(t, 0.0f), 1.0f);
            bin = d0 + t * (d1 - d0);
        }
        if (k > 0) fd[k-1][tid] = 0.5f * (bin_prev + bin);
        bin_prev = bin;
    }

    // ---- fine march = stable merge of coarse linspace + fine depths ----
    float T3 = 1.0f, sw2 = 0.0f, f0 = 0.0f, f1 = 0.0f, f2 = 0.0f, rd = 0.0f;
    int pc = 0, pf = 0;
    float dc  = NEARV;
    float dfv = fd[0][tid];
    for (int it = 0; it < PTS + IMP; it++) {
        bool tc = (pc < PTS) && (pf >= IMP || dc <= dfv);  // ties -> coarse (stable)
        float d = tc ? dc : dfv;
        if (tc) { pc++; dc = NEARV + (float)pc * STEPV; }
        else    { pf++; dfv = (pf < IMP) ? fd[pf][tid] : 3.0e38f; }
        float op = sigmoidf(base[0] + d*slp[0]);
        float v0 = sigmoidf(base[1] + d*slp[1]);
        float v1 = sigmoidf(base[2] + d*slp[2]);
        float v2 = sigmoidf(base[3] + d*slp[3]);
        float w  = op * T3;
        f0 += w*v0; f1 += w*v1; f2 += w*v2;
        sw2 += w;
        rd  += w*d;
        T3  *= (1.0f - op);
    }
    out[393216 + (b*3+0)*65536 + n] = f0;
    out[393216 + (b*3+1)*65536 + n] = f1;
    out[393216 + (b*3+2)*65536 + n] = f2;

    float fop  = fminf(fmaxf(sw2, 0.0f), 1.0f);
    float rdep = rd + (1.0f - fop) * 2.0f;     // d_all.max() == 2.0 exactly (linspace endpoint)
    out[786432 + r] = rdep;                    // raw; normalized by second kernel

    // wave-level min/max reduce, then one atomic pair per wave (positive floats:
    // u32 ordering == float ordering; min/max atomics are order-independent)
    unsigned ub = __float_as_uint(rdep);
    unsigned mn = ub, mx = ub;
    #pragma unroll
    for (int off = 32; off > 0; off >>= 1) {
        unsigned omn = (unsigned)__shfl_xor((int)mn, off, 64);
        unsigned omx = (unsigned)__shfl_xor((int)mx, off, 64);
        mn = (omn < mn) ? omn : mn;
        mx = (omx > mx) ? omx : mx;
    }
    if ((tid & 63) == 0) {
        atomicMin(&mmx[0], mn);
        atomicMax(&mmx[1], mx);
    }
}

__global__ __launch_bounds__(256) void nerf_norm(float* __restrict__ out,
                                                 const unsigned int* __restrict__ mmx)
{
    int r = blockIdx.x * 256 + threadIdx.x;
    float mn = __uint_as_float(mmx[0]);
    float mx = __uint_as_float(mmx[1]);
    float v = out[786432 + r];
    out[786432 + r] = (v - mn) / (mx - mn);
}

extern "C" void kernel_launch(void* const* d_in, const int* in_sizes, int n_in,
                              void* d_out, int out_size, void* d_ws, size_t ws_size,
                              hipStream_t stream) {
    (void)in_sizes; (void)n_in; (void)out_size; (void)ws_size;
    const float* tm = (const float*)d_in[0];
    const float* wq = (const float*)d_in[1];
    float* out = (float*)d_out;
    unsigned int* mmx = (unsigned int*)d_ws;
    // min slot -> 0x7F7F7F7F (3.39e38), max slot -> 0.0 (all depths positive)
    hipMemsetAsync(d_ws, 0x7F, 4, stream);
    hipMemsetAsync((void*)((char*)d_ws + 4), 0x00, 4, stream);
    nerf_main<<<NRAYS/NT, NT, 0, stream>>>(tm, wq, out, mmx);
    nerf_norm<<<NRAYS/256, 256, 0, stream>>>(out, mmx);
}

// Round 2
// 142.622 us; speedup vs baseline: 1.2996x; 1.2996x over previous
//
#include <hip/hip_runtime.h>
#include <math.h>

// One thread per ray. Per-ray query is affine in depth: feat[c] = base[c] + d*slope[c].
// Fast sigmoid: sigmoid(x) = rcp(1 + exp2(-x*log2e)); the -log2e factor is folded into
// the affine coefficients, so each sigmoid = fma + v_exp_f32 + add + v_rcp_f32.
// Fine depths are produced ascending by the CDF walk and consumed ascending by the
// merge -> fully fused streaming, zero LDS, occupancy VGPR-bound.

#define NT 256
#define PTS 64
#define IMP 64
#define NRAYS (2*256*256)
#define NEARV 0.1f
#define STEPV (1.9f/63.0f)
#define NL2E (-1.4426950408889634f)

extern "C" __device__ float __ocml_native_exp2_f32(float);

// arg is already -x*log2e
__device__ __forceinline__ float sig_pm(float arg) {
    return __builtin_amdgcn_rcpf(1.0f + __ocml_native_exp2_f32(arg));
}

__global__ __launch_bounds__(NT) void nerf_main(
    const float* __restrict__ tm, const float* __restrict__ wq,
    float* __restrict__ out, unsigned int* __restrict__ mmx)
{
    const int tid = threadIdx.x;
    const int r = blockIdx.x * NT + tid;
    const int b = r >> 16;          // batch
    const int n = r & 65535;        // pixel within batch
    const int i = n >> 8;           // row
    const int j = n & 255;          // col

    const float lx = 1.0f + (float)j * (-2.0f/255.0f);
    const float ly = 1.0f + (float)i * (-2.0f/255.0f);
    const float cx = lx / 4.2f;
    const float cy = ly / 4.2f;

    const float* tmb = tm + b*12;
    const float dx = tmb[0]*cx + tmb[1]*cy + tmb[2];
    const float dy = tmb[4]*cx + tmb[5]*cy + tmb[6];
    const float dz = tmb[8]*cx + tmb[9]*cy + tmb[10];
    const float ox = tmb[3], oy = tmb[7], oz = tmb[11];

    // feat[c] = base[c] + d*slope[c]; pre-fold -log2e for exp2-based sigmoid
    float bA[4], sA[4];
    #pragma unroll
    for (int c = 0; c < 4; c++) {
        float s = dx*wq[0*4+c] + dy*wq[1*4+c] + dz*wq[2*4+c];
        float bb = ox*wq[0*4+c] + oy*wq[1*4+c] + oz*wq[2*4+c]
                 + dx*wq[3*4+c] + dy*wq[4*4+c] + dz*wq[5*4+c];
        sA[c] = s * NL2E;
        bA[c] = bb * NL2E;
    }

    // ---- coarse march: accumulate c_img and S = sum(w + 1e-5) ----
    float T = 1.0f, S = 0.0f, a0 = 0.0f, a1 = 0.0f, a2 = 0.0f;
    #pragma unroll 8
    for (int p = 0; p < PTS; p++) {
        float d  = NEARV + (float)p * STEPV;
        float op = sig_pm(bA[0] + d*sA[0]);
        float v0 = sig_pm(bA[1] + d*sA[1]);
        float v1 = sig_pm(bA[2] + d*sA[2]);
        float v2 = sig_pm(bA[3] + d*sA[3]);
        float w  = op * T;
        a0 += w*v0; a1 += w*v1; a2 += w*v2;
        S  += w + 1e-5f;
        T  *= (1.0f - op);
    }
    out[(b*3+0)*65536 + n] = a0;
    out[(b*3+1)*65536 + n] = a1;
    out[(b*3+2)*65536 + n] = a2;

    // ---- CDF walk state (streaming searchsorted; invariant c_hi=cdf[ind], c_lo=cdf[ind-1]) ----
    const float Sinv = 1.0f / S;
    float T2, c_lo = 0.0f, c_hi;
    {
        float op = sig_pm(bA[0] + NEARV*sA[0]);
        c_hi = (op + 1e-5f) * Sinv;   // cdf[0]
        T2   = 1.0f - op;
    }
    int ind = 0;

    // produce bin[k] (k = 1..IMP, called in strictly ascending k)
    auto produce_bin = [&](int k) -> float {
        float u = (float)k * (1.0f/64.0f);
        while (ind < PTS && c_hi <= u) {
            ind++;
            if (ind < PTS) {
                float d  = NEARV + (float)ind * STEPV;
                float op = sig_pm(bA[0] + d*sA[0]);
                float w  = op * T2;
                T2  *= (1.0f - op);
                c_lo = c_hi;
                c_hi = c_hi + (w + 1e-5f) * Sinv;
            }
        }
        if (ind == 0)   return NEARV;                 // u below cdf[0] -> d0==d1
        if (ind >= PTS) return NEARV + 63.0f*STEPV;   // u past cdf[63] -> d63
        float d0 = NEARV + (float)(ind-1) * STEPV;
        float t = (u - c_lo) / (c_hi - c_lo);         // denom >= 1e-5/S, guard never fires
        t = fminf(fmaxf(t, 0.0f), 1.0f);
        return d0 + t * STEPV;
    };

    // ---- fine march = stable merge of coarse linspace + streamed fine depths ----
    float bin_prev = NEARV;                 // bin[0] is always NEARV (u=0 < cdf[0])
    float bnext = produce_bin(1);
    float dfv = 0.5f * (bin_prev + bnext);  // fdep[0]
    bin_prev = bnext;

    float T3 = 1.0f, sw2 = 0.0f, f0 = 0.0f, f1 = 0.0f, f2 = 0.0f, rd = 0.0f;
    int pc = 0, pf = 0;
    float dc = NEARV;
    #pragma unroll 1
    for (int it = 0; it < PTS + IMP; it++) {
        bool tc = (pc < PTS) && (pf >= IMP || dc <= dfv);  // ties -> coarse (stable)
        float d = tc ? dc : dfv;
        if (tc) {
            pc++; dc = NEARV + (float)pc * STEPV;
        } else {
            pf++;
            if (pf < IMP) {
                float bn = produce_bin(pf + 1);
                dfv = 0.5f * (bin_prev + bn);           // fdep[pf]
                bin_prev = bn;
            } else {
                dfv = 3.0e38f;
            }
        }
        float op = sig_pm(bA[0] + d*sA[0]);
        float v0 = sig_pm(bA[1] + d*sA[1]);
        float v1 = sig_pm(bA[2] + d*sA[2]);
        float v2 = sig_pm(bA[3] + d*sA[3]);
        float w  = op * T3;
        f0 += w*v0; f1 += w*v1; f2 += w*v2;
        sw2 += w;
        rd  += w*d;
        T3  *= (1.0f - op);
    }
    out[393216 + (b*3+0)*65536 + n] = f0;
    out[393216 + (b*3+1)*65536 + n] = f1;
    out[393216 + (b*3+2)*65536 + n] = f2;

    float fop  = fminf(fmaxf(sw2, 0.0f), 1.0f);
    float rdep = rd + (1.0f - fop) * 2.0f;     // d_all.max() == 2.0 exactly
    out[786432 + r] = rdep;

    // wave min/max reduce + one atomic pair per wave (positive floats: u32 order == float order)
    unsigned ub = __float_as_uint(rdep);
    unsigned mn = ub, mx = ub;
    #pragma unroll
    for (int off = 32; off > 0; off >>= 1) {
        unsigned omn = (unsigned)__shfl_xor((int)mn, off, 64);
        unsigned omx = (unsigned)__shfl_xor((int)mx, off, 64);
        mn = (omn < mn) ? omn : mn;
        mx = (omx > mx) ? omx : mx;
    }
    if ((tid & 63) == 0) {
        atomicMin(&mmx[0], mn);
        atomicMax(&mmx[1], mx);
    }
}

__global__ __launch_bounds__(256) void nerf_norm(float* __restrict__ out,
                                                 const unsigned int* __restrict__ mmx)
{
    int r = blockIdx.x * 256 + threadIdx.x;
    float mn = __uint_as_float(mmx[0]);
    float mx = __uint_as_float(mmx[1]);
    float v = out[786432 + r];
    out[786432 + r] = (v - mn) / (mx - mn);
}

extern "C" void kernel_launch(void* const* d_in, const int* in_sizes, int n_in,
                              void* d_out, int out_size, void* d_ws, size_t ws_size,
                              hipStream_t stream) {
    (void)in_sizes; (void)n_in; (void)out_size; (void)ws_size;
    const float* tm = (const float*)d_in[0];
    const float* wq = (const float*)d_in[1];
    float* out = (float*)d_out;
    unsigned int* mmx = (unsigned int*)d_ws;
    hipMemsetAsync(d_ws, 0x7F, 4, stream);                       // min slot -> 3.39e38
    hipMemsetAsync((void*)((char*)d_ws + 4), 0x00, 4, stream);   // max slot -> 0.0
    nerf_main<<<NRAYS/NT, NT, 0, stream>>>(tm, wq, out, mmx);
    nerf_norm<<<NRAYS/256, 256, 0, stream>>>(out, mmx);
}